// Round 12
// baseline (109.520 us; speedup 1.0000x reference)
//
#include <hip/hip_runtime.h>

constexpr int PIX   = 513 * 513;      // 263169 = 2056*128 + 1
constexpr int NTILE = 128;
constexpr int NFULL = PIX / NTILE;    // 2056 full tiles; 1 tail pixel
constexpr int TPB   = 4;              // tiles per block (contiguous)
constexpr int GRID  = NFULL / TPB;    // 514 blocks == 2056 tiles exactly

typedef short bf16x8 __attribute__((ext_vector_type(8)));
typedef float f32x4  __attribute__((ext_vector_type(4)));

// RNE f32 -> bf16 bits
__device__ __forceinline__ unsigned short f2bf(float f) {
    unsigned u = __builtin_bit_cast(unsigned, f);
    u += 0x7fffu + ((u >> 16) & 1u);
    return (unsigned short)(u >> 16);
}
__device__ __forceinline__ unsigned pack2(float a, float b) {
    return (unsigned)f2bf(a) | ((unsigned)f2bf(b) << 16);
}

// C[128 x P] = Wbig[128 x 128] * X[128 x P] + bias
//   X rows 0..63 = inputs_over, 64..127 = inputs_under
//   Wbig = [[w+, w-], [w-, w+]]; C rows 0..63 -> out_over, 64..127 -> out_under
// 8 waves: waves 0-3 = producers (stage X tiles), waves 4-7 = consumers (MFMA+store).
__global__ __launch_bounds__(512, 2) void mfma_bounds_kernel(
    const float* __restrict__ under,
    const float* __restrict__ over,
    const float* __restrict__ W,
    const float* __restrict__ bias,
    float* __restrict__ out_under,
    float* __restrict__ out_over)
{
    __shared__ alignas(16) unsigned short Xt[2][NTILE * 128];  // 2 x 32 KB, swizzled [px][k]

    const int t   = threadIdx.x;
    const int wv  = t >> 6;
    const int tb0 = blockIdx.x * TPB;

    if (wv < 4) {
        // ======================= PRODUCERS (threads 0..255) =======================
        // R10's proven staging mapping: thread = (px quad, k 16-row group)
        const int q   = t & 31;                   // px0 = q*4
        const int ro  = t >> 5;                   // 0..7
        const float* src = (ro < 4) ? over : under;
        const int rr  = (ro & 3) * 16;            // row within src
        const int px0 = q * 4;

        // stage tile (tb0+i) into Xt[i&1]; ld[] lives only inside this phase
#define STAGE(i)                                                               \
        {                                                                      \
            const size_t pb = (size_t)(tb0 + (i)) * NTILE + px0;               \
            f32x4 ld[16];                                                      \
            _Pragma("unroll")                                                  \
            for (int j = 0; j < 16; ++j)                                       \
                ld[j] = *(const f32x4*)(src + (size_t)(rr + j) * PIX + pb);    \
            char* bw = (char*)&Xt[(i) & 1][0];                                 \
            _Pragma("unroll")                                                  \
            for (int c = 0; c < 4; ++c) {                                      \
                const int px = px0 + c;                                        \
                const int xw = (px & 15) << 4;                                 \
                _Pragma("unroll")                                              \
                for (int oct = 0; oct < 2; ++oct) {                            \
                    int4 pk;                                                   \
                    pk.x = (int)pack2(ld[oct*8+0][c], ld[oct*8+1][c]);         \
                    pk.y = (int)pack2(ld[oct*8+2][c], ld[oct*8+3][c]);         \
                    pk.z = (int)pack2(ld[oct*8+4][c], ld[oct*8+5][c]);         \
                    pk.w = (int)pack2(ld[oct*8+6][c], ld[oct*8+7][c]);         \
                    const int kbyte = ro * 32 + oct * 16;                      \
                    *(int4*)(bw + px * 256 + (kbyte ^ xw)) = pk;               \
                }                                                              \
            }                                                                  \
        }

        STAGE(0);
        __syncthreads();                 // buf0 ready
        #pragma unroll 1
        for (int i = 0; i < TPB; ++i) {
            if (i + 1 < TPB) STAGE(i + 1);   // fills buf[(i+1)&1] while consumers read buf[i&1]
            __syncthreads();
        }
#undef STAGE
    } else {
        // ======================= CONSUMERS (threads 256..511) =====================
        const int lane = t & 63;
        const int lrow = lane & 15;
        const int lg   = lane >> 4;
        const int m0   = (wv - 4) * 32;   // consumer wave owns C rows [m0, m0+32)

        // A fragments from f32 W (L2-hot), built once — overlaps producers' STAGE(0)
        bf16x8 A[2][4];
        #pragma unroll
        for (int mt = 0; mt < 2; ++mt) {
            const int m = m0 + mt * 16 + lrow;
            const float* wr = W + (m & 63) * 64;
            #pragma unroll
            for (int ks = 0; ks < 4; ++ks) {
                const int kbase = ks * 32 + lg * 8;      // 8-aligned, never straddles 64
                const bool same = ((kbase < 64) == (m < 64));
                const float4 wa = *(const float4*)(wr + (kbase & 63));
                const float4 wb = *(const float4*)(wr + (kbase & 63) + 4);
                bf16x8 f;
                f[0] = (short)f2bf(same ? fmaxf(wa.x, 0.f) : fminf(wa.x, 0.f));
                f[1] = (short)f2bf(same ? fmaxf(wa.y, 0.f) : fminf(wa.y, 0.f));
                f[2] = (short)f2bf(same ? fmaxf(wa.z, 0.f) : fminf(wa.z, 0.f));
                f[3] = (short)f2bf(same ? fmaxf(wa.w, 0.f) : fminf(wa.w, 0.f));
                f[4] = (short)f2bf(same ? fmaxf(wb.x, 0.f) : fminf(wb.x, 0.f));
                f[5] = (short)f2bf(same ? fmaxf(wb.y, 0.f) : fminf(wb.y, 0.f));
                f[6] = (short)f2bf(same ? fmaxf(wb.z, 0.f) : fminf(wb.z, 0.f));
                f[7] = (short)f2bf(same ? fmaxf(wb.w, 0.f) : fminf(wb.w, 0.f));
                A[mt][ks] = f;
            }
        }
        float bb[2][4];
        #pragma unroll
        for (int mt = 0; mt < 2; ++mt)
            #pragma unroll
            for (int r = 0; r < 4; ++r)
                bb[mt][r] = bias[(m0 + mt * 16 + lg * 4 + r) & 63];

        __syncthreads();                 // buf0 ready

        const int xwr = lrow << 4;       // read swizzle (prow&15)<<4, prow&15 == lrow

        #pragma unroll 1
        for (int i = 0; i < TPB; ++i) {
            const char* br   = (const char*)&Xt[i & 1][0];
            const int pxbase = (tb0 + i) * NTILE;

            // mt sequential: acc[8] (32 VGPR) live at a time; B-frags re-read per mt
            #pragma unroll
            for (int mt = 0; mt < 2; ++mt) {
                f32x4 acc[8];
                #pragma unroll
                for (int nt = 0; nt < 8; ++nt) {
                    f32x4 v = {bb[mt][0], bb[mt][1], bb[mt][2], bb[mt][3]};
                    acc[nt] = v;
                }
                #pragma unroll
                for (int nt = 0; nt < 8; ++nt) {
                    const int prow = nt * 16 + lrow;
                    bf16x8 Bf[4];
                    #pragma unroll
                    for (int ks = 0; ks < 4; ++ks) {
                        const int ch = ks * 4 + lg;
                        Bf[ks] = *(const bf16x8*)(br + prow * 256 + ((ch * 16) ^ xwr));
                    }
                    #pragma unroll
                    for (int ks = 0; ks < 4; ++ks)
                        acc[nt] = __builtin_amdgcn_mfma_f32_16x16x32_bf16(
                            A[mt][ks], Bf[ks], acc[nt], 0, 0, 0);
                }
                // store: C[m][p], col = lane&15, row = lg*4 + r (verified layout)
                #pragma unroll
                for (int r = 0; r < 4; ++r) {
                    const int m = m0 + mt * 16 + lg * 4 + r;
                    float* base = (m < 64) ? (out_over  + (size_t)m        * PIX)
                                           : (out_under + (size_t)(m - 64) * PIX);
                    #pragma unroll
                    for (int nt = 0; nt < 8; ++nt)
                        __builtin_nontemporal_store(acc[nt][r],
                            base + pxbase + nt * 16 + lrow);
                }
            }
            __syncthreads();
        }
    }

    // ---- tail: single leftover pixel (PIX = 2056*128 + 1) ----
    if (blockIdx.x == GRID - 1 && t < 128) {
        const int p = NFULL * NTILE;
        const int m = t;
        const int o = m & 63;
        const float* prim = (m < 64) ? over  : under;
        const float* sec  = (m < 64) ? under : over;
        float acc = bias[o];
        for (int i = 0; i < 64; ++i) {
            const float w = W[o * 64 + i];
            acc += fmaxf(w, 0.f) * prim[(size_t)i * PIX + p]
                 + fminf(w, 0.f) * sec [(size_t)i * PIX + p];
        }
        if (m < 64) out_over [(size_t)m        * PIX + p] = acc;
        else        out_under[(size_t)(m - 64) * PIX + p] = acc;
    }
}

extern "C" void kernel_launch(void* const* d_in, const int* in_sizes, int n_in,
                              void* d_out, int out_size, void* d_ws, size_t ws_size,
                              hipStream_t stream) {
    const float* under = (const float*)d_in[0];
    const float* over  = (const float*)d_in[1];
    const float* W     = (const float*)d_in[2];
    const float* bias  = (const float*)d_in[3];
    float* out_under = (float*)d_out;
    float* out_over  = out_under + (size_t)64 * PIX;

    mfma_bounds_kernel<<<GRID, 512, 0, stream>>>(under, over, W, bias,
                                                 out_under, out_over);
}

// Round 13
// 95.521 us; speedup vs baseline: 1.1466x; 1.1466x over previous
//
#include <hip/hip_runtime.h>

constexpr int PIX   = 513 * 513;      // 263169 = 2056*128 + 1
constexpr int NTILE = 128;
constexpr int NFULL = PIX / NTILE;    // 2056 full tiles; 1 tail pixel
constexpr int GRID  = 512;            // 2 blocks/CU, persistent (~4 tiles/block)

typedef short bf16x8 __attribute__((ext_vector_type(8)));
typedef float f32x4  __attribute__((ext_vector_type(4)));

// RNE f32 -> bf16 bits
__device__ __forceinline__ unsigned short f2bf(float f) {
    unsigned u = __builtin_bit_cast(unsigned, f);
    u += 0x7fffu + ((u >> 16) & 1u);
    return (unsigned short)(u >> 16);
}
__device__ __forceinline__ unsigned pack2(float a, float b) {
    return (unsigned)f2bf(a) | ((unsigned)f2bf(b) << 16);
}

// C[128 x P] = Wbig[128 x 128] * X[128 x P] + bias
//   X rows 0..63 = inputs_over, 64..127 = inputs_under
//   Wbig = [[w+, w-], [w-, w+]]; C rows 0..63 -> out_over, 64..127 -> out_under
// Persistent: 256 threads (4 waves x 32 C-rows), double-buffered Xt, 1 barrier/tile.
__global__ __launch_bounds__(256, 2) void mfma_bounds_kernel(
    const float* __restrict__ under,
    const float* __restrict__ over,
    const float* __restrict__ W,
    const float* __restrict__ bias,
    float* __restrict__ out_under,
    float* __restrict__ out_over)
{
    __shared__ alignas(16) unsigned short Xt[2][NTILE * 128];  // 2 x 32 KB, swizzled [px][k]

    const int t    = threadIdx.x;
    const int wv   = t >> 6;        // 4 waves; wave owns C rows [wv*32, wv*32+32)
    const int lane = t & 63;
    const int lrow = lane & 15;
    const int lg   = lane >> 4;
    const int m0   = wv * 32;

    // ---- A fragments from f32 W (L2-hot). Built ONCE per block (~4 tiles). ----
    bf16x8 A[2][4];
    #pragma unroll
    for (int mt = 0; mt < 2; ++mt) {
        const int m = m0 + mt * 16 + lrow;
        const float* wr = W + (m & 63) * 64;
        #pragma unroll
        for (int ks = 0; ks < 4; ++ks) {
            const int kbase = ks * 32 + lg * 8;      // 8-aligned, never straddles 64
            const bool same = ((kbase < 64) == (m < 64));
            const float4 wa = *(const float4*)(wr + (kbase & 63));
            const float4 wb = *(const float4*)(wr + (kbase & 63) + 4);
            bf16x8 f;
            f[0] = (short)f2bf(same ? fmaxf(wa.x, 0.f) : fminf(wa.x, 0.f));
            f[1] = (short)f2bf(same ? fmaxf(wa.y, 0.f) : fminf(wa.y, 0.f));
            f[2] = (short)f2bf(same ? fmaxf(wa.z, 0.f) : fminf(wa.z, 0.f));
            f[3] = (short)f2bf(same ? fmaxf(wa.w, 0.f) : fminf(wa.w, 0.f));
            f[4] = (short)f2bf(same ? fmaxf(wb.x, 0.f) : fminf(wb.x, 0.f));
            f[5] = (short)f2bf(same ? fmaxf(wb.y, 0.f) : fminf(wb.y, 0.f));
            f[6] = (short)f2bf(same ? fmaxf(wb.z, 0.f) : fminf(wb.z, 0.f));
            f[7] = (short)f2bf(same ? fmaxf(wb.w, 0.f) : fminf(wb.w, 0.f));
            A[mt][ks] = f;
        }
    }
    float bb[2][4];
    #pragma unroll
    for (int mt = 0; mt < 2; ++mt)
        #pragma unroll
        for (int r = 0; r < 4; ++r)
            bb[mt][r] = bias[(m0 + mt * 16 + lg * 4 + r) & 63];

    // ---- staging mapping (R10/R11-proven): thread = (px quad, 16-row k group) ----
    const int q   = t & 31;                   // px0 = q*4
    const int ro  = t >> 5;                   // 0..7
    const float* src = (ro < 4) ? over : under;
    const int rr  = (ro & 3) * 16;            // row within src
    const int px0 = q * 4;
    const int xwr = lrow << 4;                // read swizzle (prow&15)<<4; prow&15==lrow

    // pack octet `oct` (8 k-rows) of ld[] into buffer b
#define PACK_OCT(b, oct)                                                     \
    {                                                                        \
        char* bw = (char*)&Xt[(b)][0];                                       \
        _Pragma("unroll")                                                    \
        for (int c = 0; c < 4; ++c) {                                        \
            const int px = px0 + c;                                          \
            const int xw = (px & 15) << 4;                                   \
            int4 pk;                                                         \
            pk.x = (int)pack2(ld[(oct)*8 + 0][c], ld[(oct)*8 + 1][c]);       \
            pk.y = (int)pack2(ld[(oct)*8 + 2][c], ld[(oct)*8 + 3][c]);       \
            pk.z = (int)pack2(ld[(oct)*8 + 4][c], ld[(oct)*8 + 5][c]);       \
            pk.w = (int)pack2(ld[(oct)*8 + 6][c], ld[(oct)*8 + 7][c]);       \
            const int kbyte = ro * 32 + (oct) * 16;                          \
            *(int4*)(bw + px * 256 + (kbyte ^ xw)) = pk;                     \
        }                                                                    \
    }

    // compute output half mt from buffer br, tile base pxbase
#define COMPUTE_MT(mt)                                                       \
    {                                                                        \
        f32x4 acc[8];                                                        \
        _Pragma("unroll")                                                    \
        for (int nt = 0; nt < 8; ++nt) {                                     \
            f32x4 v = {bb[mt][0], bb[mt][1], bb[mt][2], bb[mt][3]};          \
            acc[nt] = v;                                                     \
        }                                                                    \
        _Pragma("unroll")                                                    \
        for (int nt = 0; nt < 8; ++nt) {                                     \
            const int prow = nt * 16 + lrow;                                 \
            bf16x8 Bf[4];                                                    \
            _Pragma("unroll")                                                \
            for (int ks = 0; ks < 4; ++ks) {                                 \
                const int ch = ks * 4 + lg;                                  \
                Bf[ks] = *(const bf16x8*)(br + prow * 256 + ((ch * 16) ^ xwr)); \
            }                                                                \
            _Pragma("unroll")                                                \
            for (int ks = 0; ks < 4; ++ks)                                   \
                acc[nt] = __builtin_amdgcn_mfma_f32_16x16x32_bf16(           \
                    A[mt][ks], Bf[ks], acc[nt], 0, 0, 0);                    \
        }                                                                    \
        _Pragma("unroll")                                                    \
        for (int r = 0; r < 4; ++r) {                                        \
            const int m = m0 + (mt) * 16 + lg * 4 + r;                       \
            float* base = (m < 64) ? (out_over  + (size_t)m        * PIX)    \
                                   : (out_under + (size_t)(m - 64) * PIX);   \
            _Pragma("unroll")                                                \
            for (int nt = 0; nt < 8; ++nt)                                   \
                __builtin_nontemporal_store(acc[nt][r],                      \
                    base + pxbase + nt * 16 + lrow);                         \
        }                                                                    \
    }

    // ---- prologue: stage tile blockIdx.x -> buf0 ----
    int tile = blockIdx.x;                    // always < NFULL (512 <= 2056)
    {
        f32x4 ld[16];
        const size_t pb = (size_t)tile * NTILE + px0;
        #pragma unroll
        for (int j = 0; j < 16; ++j)
            ld[j] = *(const f32x4*)(src + (size_t)(rr + j) * PIX + pb);
        PACK_OCT(0, 0);
        PACK_OCT(0, 1);
    }
    __syncthreads();

    int cur = 0;
    for (;;) {
        const int tnext = tile + GRID;
        const bool more = tnext < NFULL;

        // issue next tile's loads up-front; latency hides under compute
        f32x4 ld[16];
        if (more) {
            const size_t pb = (size_t)tnext * NTILE + px0;
            #pragma unroll
            for (int j = 0; j < 16; ++j)
                ld[j] = *(const f32x4*)(src + (size_t)(rr + j) * PIX + pb);
        }

        const int pxbase = tile * NTILE;
        const char* br = (const char*)&Xt[cur][0];

        COMPUTE_MT(0);
        if (more) PACK_OCT(cur ^ 1, 0);   // ld[0..7] die here
        COMPUTE_MT(1);
        if (more) PACK_OCT(cur ^ 1, 1);   // ld[8..15] die here

        __syncthreads();                  // one barrier per tile
        if (!more) break;
        cur ^= 1;
        tile = tnext;
    }
#undef PACK_OCT
#undef COMPUTE_MT

    // ---- tail: single leftover pixel (PIX = 2056*128 + 1) ----
    if (blockIdx.x == GRID - 1 && t < 128) {
        const int p = NFULL * NTILE;
        const int m = t;
        const int o = m & 63;
        const float* prim = (m < 64) ? over  : under;
        const float* sec  = (m < 64) ? under : over;
        float acc = bias[o];
        for (int i = 0; i < 64; ++i) {
            const float w = W[o * 64 + i];
            acc += fmaxf(w, 0.f) * prim[(size_t)i * PIX + p]
                 + fminf(w, 0.f) * sec [(size_t)i * PIX + p];
        }
        if (m < 64) out_over [(size_t)m        * PIX + p] = acc;
        else        out_under[(size_t)(m - 64) * PIX + p] = acc;
    }
}

extern "C" void kernel_launch(void* const* d_in, const int* in_sizes, int n_in,
                              void* d_out, int out_size, void* d_ws, size_t ws_size,
                              hipStream_t stream) {
    const float* under = (const float*)d_in[0];
    const float* over  = (const float*)d_in[1];
    const float* W     = (const float*)d_in[2];
    const float* bias  = (const float*)d_in[3];
    float* out_under = (float*)d_out;
    float* out_over  = out_under + (size_t)64 * PIX;

    mfma_bounds_kernel<<<GRID, 256, 0, stream>>>(under, over, W, bias,
                                                 out_under, out_over);
}

// Round 14
// 88.611 us; speedup vs baseline: 1.2360x; 1.0780x over previous
//
#include <hip/hip_runtime.h>

constexpr int PIX   = 513 * 513;  // 263169 = 2056*128 + 1
constexpr int NTILE = 128;        // pixels per block

typedef short    bf16x8 __attribute__((ext_vector_type(8)));
typedef float    f32x4  __attribute__((ext_vector_type(4)));
typedef unsigned u32x4  __attribute__((ext_vector_type(4)));

// RNE f32 -> bf16 bits (used for weights only; cheap, once per block)
__device__ __forceinline__ unsigned short f2bf(float f) {
    unsigned u = __builtin_bit_cast(unsigned, f);
    u += 0x7fffu + ((u >> 16) & 1u);
    return (unsigned short)(u >> 16);
}

// round-half-up pack of two f32 into (bf16(a) | bf16(b)<<16) — 2 add + 1 v_perm
__device__ __forceinline__ unsigned packrhu(float a, float b) {
    const unsigned ua = __builtin_bit_cast(unsigned, a) + 0x8000u;
    const unsigned ub = __builtin_bit_cast(unsigned, b) + 0x8000u;
    // {ub,ua} bytes: ua=0..3, ub=4..7; take ua.b2,ua.b3,ub.b2,ub.b3
    return __builtin_amdgcn_perm(ub, ua, 0x07060302u);
}

// C[128 x P] = Wbig[128 x 128] * X[128 x P] + bias
//   X rows 0..63 = inputs_over, 64..127 = inputs_under
//   Wbig = [[w+, w-], [w-, w+]]; C rows 0..63 -> out_over, 64..127 -> out_under
// NO LDS, NO barriers: B-fragments gathered directly from global (coalesced
// 4x64B segments/instr); every wave is an independent load->cvt->MFMA pipeline.
__global__ __launch_bounds__(256, 2) void mfma_bounds_kernel(
    const float* __restrict__ under,
    const float* __restrict__ over,
    const float* __restrict__ W,
    const float* __restrict__ bias,
    float* __restrict__ out_under,
    float* __restrict__ out_over)
{
    const int t = threadIdx.x;
    const int pxbase = blockIdx.x * NTILE;

    if (pxbase + NTILE > PIX) {
        // ---- tail block (1 pixel): scalar f32 path ----
        if (t < 128) {
            const int m = t;
            const int o = m & 63;
            const float* prim = (m < 64) ? over  : under;
            const float* sec  = (m < 64) ? under : over;
            for (int p = pxbase; p < PIX; ++p) {
                float acc = bias[o];
                for (int i = 0; i < 64; ++i) {
                    const float w = W[o * 64 + i];
                    acc += fmaxf(w, 0.f) * prim[(size_t)i * PIX + p]
                         + fminf(w, 0.f) * sec [(size_t)i * PIX + p];
                }
                if (m < 64) out_over [(size_t)m        * PIX + p] = acc;
                else        out_under[(size_t)(m - 64) * PIX + p] = acc;
            }
        }
        return;
    }

    const int wv   = t >> 6;       // 4 waves; wave owns C rows [wv*32, wv*32+32)
    const int lane = t & 63;
    const int lrow = lane & 15;
    const int lg   = lane >> 4;
    const int m0   = wv * 32;

    // ---- A fragments from f32 W (16 KB, L1-hot). Once per block. ----
    bf16x8 A[2][4];
    #pragma unroll
    for (int mt = 0; mt < 2; ++mt) {
        const int m = m0 + mt * 16 + lrow;
        const float* wr = W + (m & 63) * 64;
        #pragma unroll
        for (int ks = 0; ks < 4; ++ks) {
            const int kbase = ks * 32 + lg * 8;      // 8-aligned, never straddles 64
            const bool same = ((kbase < 64) == (m < 64));
            const float4 wa = *(const float4*)(wr + (kbase & 63));
            const float4 wb = *(const float4*)(wr + (kbase & 63) + 4);
            bf16x8 f;
            f[0] = (short)f2bf(same ? fmaxf(wa.x, 0.f) : fminf(wa.x, 0.f));
            f[1] = (short)f2bf(same ? fmaxf(wa.y, 0.f) : fminf(wa.y, 0.f));
            f[2] = (short)f2bf(same ? fmaxf(wa.z, 0.f) : fminf(wa.z, 0.f));
            f[3] = (short)f2bf(same ? fmaxf(wa.w, 0.f) : fminf(wa.w, 0.f));
            f[4] = (short)f2bf(same ? fmaxf(wb.x, 0.f) : fminf(wb.x, 0.f));
            f[5] = (short)f2bf(same ? fmaxf(wb.y, 0.f) : fminf(wb.y, 0.f));
            f[6] = (short)f2bf(same ? fmaxf(wb.z, 0.f) : fminf(wb.z, 0.f));
            f[7] = (short)f2bf(same ? fmaxf(wb.w, 0.f) : fminf(wb.w, 0.f));
            A[mt][ks] = f;
        }
    }
    float bb[2][4];
    #pragma unroll
    for (int mt = 0; mt < 2; ++mt)
        #pragma unroll
        for (int r = 0; r < 4; ++r)
            bb[mt][r] = bias[(m0 + mt * 16 + lg * 4 + r) & 63];

    // ---- two nt-halves of 4: acc[2][4] = 32 VGPR live ----
    #pragma unroll
    for (int h = 0; h < 2; ++h) {
        f32x4 acc[2][4];
        #pragma unroll
        for (int mt = 0; mt < 2; ++mt)
            #pragma unroll
            for (int n4 = 0; n4 < 4; ++n4) {
                f32x4 v = {bb[mt][0], bb[mt][1], bb[mt][2], bb[mt][3]};
                acc[mt][n4] = v;
            }

        #pragma unroll
        for (int n4 = 0; n4 < 4; ++n4) {
            const int nt = h * 4 + n4;
            const size_t cb = (size_t)pxbase + nt * 16 + lrow;  // this lane's px

            // batch all 32 B-loads for this nt (4 frags x 8 k) -> in flight together
            float va[4][8];
            #pragma unroll
            for (int ks = 0; ks < 4; ++ks) {
                const float* sp = (ks < 2) ? over : under;
                const int r0 = (ks & 1) * 32 + lg * 8;   // row within sp
                #pragma unroll
                for (int e = 0; e < 8; ++e)
                    va[ks][e] = sp[(size_t)(r0 + e) * PIX + cb];
            }

            #pragma unroll
            for (int ks = 0; ks < 4; ++ks) {
                u32x4 p;
                p[0] = packrhu(va[ks][0], va[ks][1]);
                p[1] = packrhu(va[ks][2], va[ks][3]);
                p[2] = packrhu(va[ks][4], va[ks][5]);
                p[3] = packrhu(va[ks][6], va[ks][7]);
                const bf16x8 fr = __builtin_bit_cast(bf16x8, p);
                #pragma unroll
                for (int mt = 0; mt < 2; ++mt)
                    acc[mt][n4] = __builtin_amdgcn_mfma_f32_16x16x32_bf16(
                        A[mt][ks], fr, acc[mt][n4], 0, 0, 0);
            }
        }

        // ---- store this half: C[m][p], col = lane&15, row = lg*4 + r ----
        #pragma unroll
        for (int mt = 0; mt < 2; ++mt)
            #pragma unroll
            for (int r = 0; r < 4; ++r) {
                const int m = m0 + mt * 16 + lg * 4 + r;
                float* base = (m < 64) ? (out_over  + (size_t)m        * PIX)
                                       : (out_under + (size_t)(m - 64) * PIX);
                #pragma unroll
                for (int n4 = 0; n4 < 4; ++n4)
                    __builtin_nontemporal_store(acc[mt][n4][r],
                        base + pxbase + (h * 4 + n4) * 16 + lrow);
            }
    }
}

extern "C" void kernel_launch(void* const* d_in, const int* in_sizes, int n_in,
                              void* d_out, int out_size, void* d_ws, size_t ws_size,
                              hipStream_t stream) {
    const float* under = (const float*)d_in[0];
    const float* over  = (const float*)d_in[1];
    const float* W     = (const float*)d_in[2];
    const float* bias  = (const float*)d_in[3];
    float* out_under = (float*)d_out;
    float* out_over  = out_under + (size_t)64 * PIX;

    const int blocks = (PIX + NTILE - 1) / NTILE;  // 2057
    mfma_bounds_kernel<<<blocks, 256, 0, stream>>>(under, over, W, bias,
                                                   out_under, out_over);
}